// Round 4
// baseline (246.583 us; speedup 1.0000x reference)
//
#include <hip/hip_runtime.h>

#define HD 32
#define QCH 8          // channels per thread (quarter of head_dim)
#define NQ 4           // channel quarters
#define NHEADS 12
#define HH 56
#define WW 56
#define NN (HH * WW)
#define BB 8
#define CC (HD * NHEADS)
#define PAIRS_PER_BLK 64
#define NPAIRS (NN / 2)    // 1568
#define SCALE 0.17677669529663689f

// block (64,4)=256 threads, 4 blocks/CU (launch_bounds -> 128 VGPR budget).
// Each thread: 2 consecutive pixels (float2) x 8 channels. Loads are
// unconditional (clamped addresses + mask-multiply) and batched 3-taps-deep
// (24 float2 = 12 KB in flight per wave) to maximize MLP.
__global__ __launch_bounds__(256, 4) void dilate_attn_kernel(
    const float* __restrict__ q,
    const float* __restrict__ k,
    const float* __restrict__ v,
    float* __restrict__ out)
{
    const int xi = threadIdx.x;           // 0..63 : pair within block
    const int qtr = threadIdx.y;          // 0..3  : channel quarter
    const int pair = blockIdx.x * PAIRS_PER_BLK + xi;
    const bool active = (pair < NPAIRS);
    const int pc = active ? pair : (NPAIRS - 1);
    const int n0 = 2 * pc;
    const int y = n0 / WW;
    const int x0 = n0 - y * WW;           // even

    const int bh = blockIdx.y;
    const int b = bh / NHEADS;
    const int head = bh - b * NHEADS;

    const size_t base = ((size_t)b * CC + (size_t)head * HD + (size_t)qtr * QCH) * NN;

    // tap geometry: clamped offsets + validity masks (no divergent loads)
    int offs[9];
    float msk[9];
#pragma unroll
    for (int t = 0; t < 9; ++t) {
        const int dy = ((t / 3) - 1) * 2;
        const int dx = ((t % 3) - 1) * 2;
        const int ny = y + dy;
        const int nx = x0 + dx;
        const bool ok = ((unsigned)ny < HH) && ((unsigned)nx < (WW - 1));
        const int nyc = min(max(ny, 0), HH - 1);
        const int nxc = min(max(nx, 0), WW - 2);
        offs[t] = nyc * WW + nxc;
        msk[t] = ok ? 1.f : 0.f;
    }

    __shared__ float2 part[NQ][9][PAIRS_PER_BLK];   // 18432 B

    // q fragment: 8 float2, unconditional
    float2 qv[QCH];
    {
        const float* qb = q + base + n0;
#pragma unroll
        for (int d = 0; d < QCH; ++d)
            qv[d] = *reinterpret_cast<const float2*>(qb + (size_t)d * NN);
    }

    // QK: process taps in rows of 3; load all 24 float2 before FMAs
    float2 lg[9];
#pragma unroll
    for (int tr = 0; tr < 3; ++tr) {
        float2 kb[3][QCH];
#pragma unroll
        for (int j = 0; j < 3; ++j) {
            const float* kp = k + base + offs[tr * 3 + j];
#pragma unroll
            for (int d = 0; d < QCH; ++d)
                kb[j][d] = *reinterpret_cast<const float2*>(kp + (size_t)d * NN);
        }
#pragma unroll
        for (int j = 0; j < 3; ++j) {
            float sx = 0.f, sy = 0.f;
#pragma unroll
            for (int d = 0; d < QCH; ++d) {
                sx = fmaf(qv[d].x, kb[j][d].x, sx);
                sy = fmaf(qv[d].y, kb[j][d].y, sy);
            }
            lg[tr * 3 + j] = make_float2(sx, sy);
        }
    }
#pragma unroll
    for (int t = 0; t < 9; ++t) part[qtr][t][xi] = lg[t];
    __syncthreads();

    // combine quarters; apply scale + validity mask once
#pragma unroll
    for (int o = 1; o < NQ; ++o) {
        const int oq = (qtr + o) & 3;
#pragma unroll
        for (int t = 0; t < 9; ++t) {
            const float2 p = part[oq][t][xi];
            lg[t].x += p.x;
            lg[t].y += p.y;
        }
    }
#pragma unroll
    for (int t = 0; t < 9; ++t) {
        const float sm = SCALE * msk[t];
        lg[t].x *= sm;
        lg[t].y *= sm;
    }

    // softmax over 9 taps (componentwise; OOB logits = 0 participate)
    float mx = lg[0].x, my = lg[0].y;
#pragma unroll
    for (int t = 1; t < 9; ++t) { mx = fmaxf(mx, lg[t].x); my = fmaxf(my, lg[t].y); }
    float sx = 0.f, sy = 0.f;
#pragma unroll
    for (int t = 0; t < 9; ++t) {
        lg[t].x = __expf(lg[t].x - mx); sx += lg[t].x;
        lg[t].y = __expf(lg[t].y - my); sy += lg[t].y;
    }
    const float ix = 1.f / sx, iy = 1.f / sy;

    // PV weights (masked: OOB taps contribute no V)
    float wx[9], wy[9];
#pragma unroll
    for (int t = 0; t < 9; ++t) {
        wx[t] = lg[t].x * ix * msk[t];
        wy[t] = lg[t].y * iy * msk[t];
    }

    // PV: same 3-tap batched loads
    float2 acc[QCH];
#pragma unroll
    for (int d = 0; d < QCH; ++d) acc[d] = make_float2(0.f, 0.f);
#pragma unroll
    for (int tr = 0; tr < 3; ++tr) {
        float2 vb[3][QCH];
#pragma unroll
        for (int j = 0; j < 3; ++j) {
            const float* vp = v + base + offs[tr * 3 + j];
#pragma unroll
            for (int d = 0; d < QCH; ++d)
                vb[j][d] = *reinterpret_cast<const float2*>(vp + (size_t)d * NN);
        }
#pragma unroll
        for (int j = 0; j < 3; ++j) {
            const int t = tr * 3 + j;
#pragma unroll
            for (int d = 0; d < QCH; ++d) {
                acc[d].x = fmaf(wx[t], vb[j][d].x, acc[d].x);
                acc[d].y = fmaf(wy[t], vb[j][d].y, acc[d].y);
            }
        }
    }

    // out[b, n, head*32 + qtr*8 + d]: 8 contiguous floats per pixel
    if (active) {
        float* ob0 = out + ((size_t)b * NN + n0) * CC + (size_t)head * HD + (size_t)qtr * QCH;
        float* ob1 = ob0 + CC;
        float4 s0 = make_float4(acc[0].x, acc[1].x, acc[2].x, acc[3].x);
        float4 s1 = make_float4(acc[4].x, acc[5].x, acc[6].x, acc[7].x);
        float4 s2 = make_float4(acc[0].y, acc[1].y, acc[2].y, acc[3].y);
        float4 s3 = make_float4(acc[4].y, acc[5].y, acc[6].y, acc[7].y);
        reinterpret_cast<float4*>(ob0)[0] = s0;
        reinterpret_cast<float4*>(ob0)[1] = s1;
        reinterpret_cast<float4*>(ob1)[0] = s2;
        reinterpret_cast<float4*>(ob1)[1] = s3;
    }
}

extern "C" void kernel_launch(void* const* d_in, const int* in_sizes, int n_in,
                              void* d_out, int out_size, void* d_ws, size_t ws_size,
                              hipStream_t stream) {
    const float* q = (const float*)d_in[0];
    const float* k = (const float*)d_in[1];
    const float* v = (const float*)d_in[2];
    float* out = (float*)d_out;

    dim3 block(PAIRS_PER_BLK, NQ);
    dim3 grid((NPAIRS + PAIRS_PER_BLK - 1) / PAIRS_PER_BLK, BB * NHEADS);
    dilate_attn_kernel<<<grid, block, 0, stream>>>(q, k, v, out);
}

// Round 5
// 191.657 us; speedup vs baseline: 1.2866x; 1.2866x over previous
//
#include <hip/hip_runtime.h>

#define HD 32
#define QCH 8          // channels per thread (quarter of head_dim)
#define NQ 4           // channel quarters
#define NHEADS 12
#define HH 56
#define WW 56
#define NN (HH * WW)
#define BB 8
#define CC (HD * NHEADS)
#define PAIRS_PER_BLK 64
#define NPAIRS (NN / 2)    // 1568
#define SCALE 0.17677669529663689f

// block (64,4)=256 threads. Each thread: 2 consecutive pixels (float2) x 8
// channels. All loads unconditional (clamped addr + mask multiply).
// Double-buffered tap pipeline: tap t+1's 8 float2 loads are in flight while
// tap t's 16 FMAs execute -> per-wave MLP ~8 instead of ~1.
// No min-waves launch bound: let the allocator take ~112 VGPRs w/o spilling.
__global__ __launch_bounds__(256) void dilate_attn_kernel(
    const float* __restrict__ q,
    const float* __restrict__ k,
    const float* __restrict__ v,
    float* __restrict__ out)
{
    const int xi = threadIdx.x;           // 0..63 : pair within block
    const int qtr = threadIdx.y;          // 0..3  : channel quarter
    const int pair = blockIdx.x * PAIRS_PER_BLK + xi;
    const bool active = (pair < NPAIRS);
    const int pc = active ? pair : (NPAIRS - 1);
    const int n0 = 2 * pc;
    const int y = n0 / WW;
    const int x0 = n0 - y * WW;           // even

    const int bh = blockIdx.y;
    const int b = bh / NHEADS;
    const int head = bh - b * NHEADS;

    const size_t base = ((size_t)b * CC + (size_t)head * HD + (size_t)qtr * QCH) * NN;

    // clamped tap offsets + validity masks (loads never branch)
    int offs[9];
    float msk[9];
#pragma unroll
    for (int t = 0; t < 9; ++t) {
        const int dy = ((t / 3) - 1) * 2;
        const int dx = ((t % 3) - 1) * 2;
        const int ny = y + dy;
        const int nx = x0 + dx;
        const bool ok = ((unsigned)ny < HH) && ((unsigned)nx < (WW - 1));
        const int nyc = min(max(ny, 0), HH - 1);
        const int nxc = min(max(nx, 0), WW - 2);
        offs[t] = nyc * WW + nxc;
        msk[t] = ok ? 1.f : 0.f;
    }

    __shared__ float2 part[NQ][9][PAIRS_PER_BLK];   // 18432 B

    // q fragment: 8 float2, unconditional
    float2 qv[QCH];
    {
        const float* qb = q + base + n0;
#pragma unroll
        for (int d = 0; d < QCH; ++d)
            qv[d] = *reinterpret_cast<const float2*>(qb + (size_t)d * NN);
    }

    // ---- QK with double-buffered tap loads ----
    float2 lg[9];
    float2 buf0[QCH], buf1[QCH];
    {
        const float* kp0 = k + base + offs[0];
#pragma unroll
        for (int d = 0; d < QCH; ++d)
            buf0[d] = *reinterpret_cast<const float2*>(kp0 + (size_t)d * NN);
    }
#pragma unroll
    for (int t = 0; t < 9; ++t) {
        // prefetch tap t+1 into the other buffer
        if (t < 8) {
            const float* kp = k + base + offs[t + 1];
            if (t & 1) {
#pragma unroll
                for (int d = 0; d < QCH; ++d)
                    buf0[d] = *reinterpret_cast<const float2*>(kp + (size_t)d * NN);
            } else {
#pragma unroll
                for (int d = 0; d < QCH; ++d)
                    buf1[d] = *reinterpret_cast<const float2*>(kp + (size_t)d * NN);
            }
        }
        // consume tap t
        float sx = 0.f, sy = 0.f;
        if (t & 1) {
#pragma unroll
            for (int d = 0; d < QCH; ++d) {
                sx = fmaf(qv[d].x, buf1[d].x, sx);
                sy = fmaf(qv[d].y, buf1[d].y, sy);
            }
        } else {
#pragma unroll
            for (int d = 0; d < QCH; ++d) {
                sx = fmaf(qv[d].x, buf0[d].x, sx);
                sy = fmaf(qv[d].y, buf0[d].y, sy);
            }
        }
        lg[t] = make_float2(sx, sy);
    }
#pragma unroll
    for (int t = 0; t < 9; ++t) part[qtr][t][xi] = lg[t];
    __syncthreads();

    // combine quarters; scale + mask
#pragma unroll
    for (int o = 1; o < NQ; ++o) {
        const int oq = (qtr + o) & 3;
#pragma unroll
        for (int t = 0; t < 9; ++t) {
            const float2 p = part[oq][t][xi];
            lg[t].x += p.x;
            lg[t].y += p.y;
        }
    }
#pragma unroll
    for (int t = 0; t < 9; ++t) {
        const float sm = SCALE * msk[t];
        lg[t].x *= sm;
        lg[t].y *= sm;
    }

    // softmax over 9 taps (OOB logits participate as 0, matching zero-pad ref)
    float mx = lg[0].x, my = lg[0].y;
#pragma unroll
    for (int t = 1; t < 9; ++t) { mx = fmaxf(mx, lg[t].x); my = fmaxf(my, lg[t].y); }
    float sx = 0.f, sy = 0.f;
#pragma unroll
    for (int t = 0; t < 9; ++t) {
        lg[t].x = __expf(lg[t].x - mx); sx += lg[t].x;
        lg[t].y = __expf(lg[t].y - my); sy += lg[t].y;
    }
    const float ix = 1.f / sx, iy = 1.f / sy;
#pragma unroll
    for (int t = 0; t < 9; ++t) {        // lg becomes PV weights (masked)
        lg[t].x *= ix * msk[t];
        lg[t].y *= iy * msk[t];
    }

    // ---- PV with double-buffered tap loads ----
    float2 acc[QCH];
#pragma unroll
    for (int d = 0; d < QCH; ++d) acc[d] = make_float2(0.f, 0.f);
    {
        const float* vp0 = v + base + offs[0];
#pragma unroll
        for (int d = 0; d < QCH; ++d)
            buf0[d] = *reinterpret_cast<const float2*>(vp0 + (size_t)d * NN);
    }
#pragma unroll
    for (int t = 0; t < 9; ++t) {
        if (t < 8) {
            const float* vp = v + base + offs[t + 1];
            if (t & 1) {
#pragma unroll
                for (int d = 0; d < QCH; ++d)
                    buf0[d] = *reinterpret_cast<const float2*>(vp + (size_t)d * NN);
            } else {
#pragma unroll
                for (int d = 0; d < QCH; ++d)
                    buf1[d] = *reinterpret_cast<const float2*>(vp + (size_t)d * NN);
            }
        }
        const float wx = lg[t].x, wy = lg[t].y;
        if (t & 1) {
#pragma unroll
            for (int d = 0; d < QCH; ++d) {
                acc[d].x = fmaf(wx, buf1[d].x, acc[d].x);
                acc[d].y = fmaf(wy, buf1[d].y, acc[d].y);
            }
        } else {
#pragma unroll
            for (int d = 0; d < QCH; ++d) {
                acc[d].x = fmaf(wx, buf0[d].x, acc[d].x);
                acc[d].y = fmaf(wy, buf0[d].y, acc[d].y);
            }
        }
    }

    // out[b, n, head*32 + qtr*8 + d]: 8 contiguous floats per pixel
    if (active) {
        float* ob0 = out + ((size_t)b * NN + n0) * CC + (size_t)head * HD + (size_t)qtr * QCH;
        float* ob1 = ob0 + CC;
        float4 s0 = make_float4(acc[0].x, acc[1].x, acc[2].x, acc[3].x);
        float4 s1 = make_float4(acc[4].x, acc[5].x, acc[6].x, acc[7].x);
        float4 s2 = make_float4(acc[0].y, acc[1].y, acc[2].y, acc[3].y);
        float4 s3 = make_float4(acc[4].y, acc[5].y, acc[6].y, acc[7].y);
        reinterpret_cast<float4*>(ob0)[0] = s0;
        reinterpret_cast<float4*>(ob0)[1] = s1;
        reinterpret_cast<float4*>(ob1)[0] = s2;
        reinterpret_cast<float4*>(ob1)[1] = s3;
    }
}

extern "C" void kernel_launch(void* const* d_in, const int* in_sizes, int n_in,
                              void* d_out, int out_size, void* d_ws, size_t ws_size,
                              hipStream_t stream) {
    const float* q = (const float*)d_in[0];
    const float* k = (const float*)d_in[1];
    const float* v = (const float*)d_in[2];
    float* out = (float*)d_out;

    dim3 block(PAIRS_PER_BLK, NQ);
    dim3 grid((NPAIRS + PAIRS_PER_BLK - 1) / PAIRS_PER_BLK, BB * NHEADS);
    dilate_attn_kernel<<<grid, block, 0, stream>>>(q, k, v, out);
}